// Round 1
// baseline (798.802 us; speedup 1.0000x reference)
//
#include <hip/hip_runtime.h>
#include <cstdint>
#include <cstddef>

typedef __attribute__((ext_vector_type(8))) short bf16x8;
typedef __attribute__((ext_vector_type(4))) float f32x4;

__device__ __forceinline__ unsigned short f2bf(float f) {
    union { float f; unsigned int u; } v; v.f = f;
    unsigned int r = v.u + 0x7FFFu + ((v.u >> 16) & 1u);
    return (unsigned short)(r >> 16);
}
__device__ __forceinline__ unsigned int pk2(float a, float b) {
    return (unsigned int)f2bf(a) | ((unsigned int)f2bf(b) << 16);
}

#define LDT 72  // LDS row stride (elements): 144 B -> 2-way bank aliasing (free), 16B-aligned

// ---------------------------------------------------------------------------
// Weight prep: W[k][n] fp32 -> Wt[n][k] bf16 for Wq,Wk,Wv,Wo (all 1024x1024)
// ---------------------------------------------------------------------------
__global__ __launch_bounds__(256)
void prep_weights(const float* __restrict__ W0, const float* __restrict__ W1,
                  const float* __restrict__ W2, const float* __restrict__ W3,
                  unsigned short* __restrict__ T0, unsigned short* __restrict__ T1,
                  unsigned short* __restrict__ T2, unsigned short* __restrict__ T3)
{
    __shared__ float t[32][33];
    const int z = blockIdx.z;
    const float* W = (z == 0) ? W0 : (z == 1) ? W1 : (z == 2) ? W2 : W3;
    unsigned short* Wt = (z == 0) ? T0 : (z == 1) ? T1 : (z == 2) ? T2 : T3;
    const int n0 = blockIdx.x * 32, k0 = blockIdx.y * 32;
    const int tx = threadIdx.x & 31, ty = threadIdx.x >> 5;  // 32 x 8
#pragma unroll
    for (int i = 0; i < 4; i++)
        t[ty + 8 * i][tx] = W[(size_t)(k0 + ty + 8 * i) * 1024 + n0 + tx];
    __syncthreads();
#pragma unroll
    for (int i = 0; i < 4; i++)
        Wt[(size_t)(n0 + ty + 8 * i) * 1024 + k0 + tx] = f2bf(t[tx][ty + 8 * i]);
}

// ---------------------------------------------------------------------------
// 128x128 bf16 MFMA GEMM, M=8192 N=1024 K=1024.
// MODE 0: A=fp32, out bf16 [B,H,S,64]   (q)
// MODE 1: A=fp32, out bf16 [B,H,S,64]   (k)
// MODE 2: A=fp32, out bf16 [B,H,64,S]   (v transposed)
// MODE 3: A=bf16 (ctx),  out fp32 [M,N] + bias (final)
// ---------------------------------------------------------------------------
template <int MODE>
__global__ __launch_bounds__(256, 2)
void gemm128(const float* __restrict__ A32, const unsigned short* __restrict__ A16,
             const unsigned short* __restrict__ Wt, const float* __restrict__ bias,
             unsigned short* __restrict__ ob, float* __restrict__ of)
{
    __shared__ __align__(16) unsigned short sm[2 * 128 * LDT];  // 36864 B
    unsigned short* As = sm;
    unsigned short* Bs = sm + 128 * LDT;

    const int tid  = threadIdx.x;
    const int lane = tid & 63;
    const int wave = tid >> 6;
    const int quad = lane >> 4;
    const int l16  = lane & 15;
    const int wr   = wave >> 1;
    const int wc   = wave & 1;

    const int m0 = blockIdx.x * 128;
    const int n0 = blockIdx.y * 128;

    const int sr = tid >> 1;         // staging row 0..127
    const int sh = (tid & 1) << 4;   // element offset 0/16

    f32x4 acc[4][4];
#pragma unroll
    for (int i = 0; i < 4; i++)
#pragma unroll
        for (int j = 0; j < 4; j++) acc[i][j] = (f32x4){0.f, 0.f, 0.f, 0.f};

    for (int kk = 0; kk < 1024; kk += 32) {
        // ---- stage A (fp32 -> bf16, or bf16 passthrough) ----
        if (MODE < 3) {
            const float* g = A32 + (size_t)(m0 + sr) * 1024 + kk + sh;
            float4 a0 = *(const float4*)(g);
            float4 a1 = *(const float4*)(g + 4);
            float4 a2 = *(const float4*)(g + 8);
            float4 a3 = *(const float4*)(g + 12);
            uint4 p0, p1;
            p0.x = pk2(a0.x, a0.y); p0.y = pk2(a0.z, a0.w);
            p0.z = pk2(a1.x, a1.y); p0.w = pk2(a1.z, a1.w);
            p1.x = pk2(a2.x, a2.y); p1.y = pk2(a2.z, a2.w);
            p1.z = pk2(a3.x, a3.y); p1.w = pk2(a3.z, a3.w);
            *(uint4*)&As[sr * LDT + sh]     = p0;
            *(uint4*)&As[sr * LDT + sh + 8] = p1;
        } else {
            const uint4* g = (const uint4*)(A16 + (size_t)(m0 + sr) * 1024 + kk + sh);
            *(uint4*)&As[sr * LDT + sh]     = g[0];
            *(uint4*)&As[sr * LDT + sh + 8] = g[1];
        }
        // ---- stage B from Wt[n][k] (bf16) ----
        {
            const uint4* g = (const uint4*)(Wt + (size_t)(n0 + sr) * 1024 + kk + sh);
            *(uint4*)&Bs[sr * LDT + sh]     = g[0];
            *(uint4*)&Bs[sr * LDT + sh + 8] = g[1];
        }
        __syncthreads();

        bf16x8 af[4], bfr[4];
#pragma unroll
        for (int mt = 0; mt < 4; mt++)
            af[mt] = *(const bf16x8*)&As[(wr * 64 + mt * 16 + l16) * LDT + quad * 8];
#pragma unroll
        for (int nt = 0; nt < 4; nt++)
            bfr[nt] = *(const bf16x8*)&Bs[(wc * 64 + nt * 16 + l16) * LDT + quad * 8];
#pragma unroll
        for (int mt = 0; mt < 4; mt++)
#pragma unroll
            for (int nt = 0; nt < 4; nt++)
                acc[mt][nt] = __builtin_amdgcn_mfma_f32_16x16x32_bf16(af[mt], bfr[nt], acc[mt][nt], 0, 0, 0);
        __syncthreads();
    }

    float bv[4];
#pragma unroll
    for (int nt = 0; nt < 4; nt++) bv[nt] = bias[n0 + wc * 64 + nt * 16 + l16];

    if (MODE == 3) {
#pragma unroll
        for (int mt = 0; mt < 4; mt++) {
            const int m = m0 + wr * 64 + mt * 16 + quad * 4;
#pragma unroll
            for (int nt = 0; nt < 4; nt++) {
                const int n = n0 + wc * 64 + nt * 16 + l16;
#pragma unroll
                for (int r = 0; r < 4; r++)
                    of[(size_t)(m + r) * 1024 + n] = acc[mt][nt][r] + bv[nt];
            }
        }
    } else if (MODE == 0 || MODE == 1) {
#pragma unroll
        for (int mt = 0; mt < 4; mt++) {
            const int m = m0 + wr * 64 + mt * 16 + quad * 4;
            const int b = m >> 11;
#pragma unroll
            for (int nt = 0; nt < 4; nt++) {
                const int n = n0 + wc * 64 + nt * 16 + l16;
                const int h = n >> 6, dk = n & 63;
#pragma unroll
                for (int r = 0; r < 4; r++) {
                    const int s = (m + r) & 2047;
                    ob[((size_t)((b << 4) + h) * 2048 + s) * 64 + dk] = f2bf(acc[mt][nt][r] + bv[nt]);
                }
            }
        }
    } else {  // MODE 2: write V transposed [B,H,DV,S] via LDS transpose (coalesced 16B stores)
        unsigned short* T = sm + wave * (64 * LDT);  // 4 x 4608 elems = whole sm, per-wave
#pragma unroll
        for (int mt = 0; mt < 4; mt++)
#pragma unroll
            for (int nt = 0; nt < 4; nt++)
#pragma unroll
                for (int r = 0; r < 4; r++)
                    T[(nt * 16 + l16) * LDT + mt * 16 + quad * 4 + r] = f2bf(acc[mt][nt][r] + bv[nt]);
        __syncthreads();
#pragma unroll
        for (int i = 0; i < 8; i++) {
            const int nl = i * 8 + (lane >> 3);
            const int mc = lane & 7;
            uint4 v = *(const uint4*)&T[nl * LDT + mc * 8];
            const int n  = n0 + wc * 64 + nl;
            const int mg = m0 + wr * 64 + mc * 8;
            const int b = mg >> 11, s = mg & 2047;
            const int h = n >> 6, dv = n & 63;
            *(uint4*)&ob[((size_t)((b << 4) + h) * 64 + dv) * 2048 + s] = v;
        }
    }
}

// ---------------------------------------------------------------------------
// Flash attention: block = 64 Q rows (4 independent waves x 16 rows), loop
// over 32 K-tiles of 64. q,k bf16 [B,H,S,64]; vT bf16 [B,H,64,S]; mask fp32.
// ---------------------------------------------------------------------------
__global__ __launch_bounds__(256, 2)
void attn_kernel(const unsigned short* __restrict__ q,
                 const unsigned short* __restrict__ k,
                 const unsigned short* __restrict__ vT,
                 const float* __restrict__ mask,
                 unsigned short* __restrict__ ctx)
{
    __shared__ __align__(16) unsigned short P[4][16 * LDT];  // per-wave P tile
    const int tid = threadIdx.x, lane = tid & 63, wave = tid >> 6;
    const int quad = lane >> 4, l16 = lane & 15;
    const int bid = blockIdx.x;
    const int qt = bid & 31, h = (bid >> 5) & 15, b = bid >> 9;
    const int q0 = qt * 64 + wave * 16;

    const unsigned short* qb = q  + (size_t)(b * 16 + h) * 2048 * 64;
    const unsigned short* kb = k  + (size_t)(b * 16 + h) * 2048 * 64;
    const unsigned short* vb = vT + (size_t)(b * 16 + h) * 64 * 2048;
    const int moff = (q0 + quad * 4) * 2048 + l16;  // mask base for reg r: +r*2048

    bf16x8 qf[2];
#pragma unroll
    for (int ks = 0; ks < 2; ks++)
        qf[ks] = *(const bf16x8*)&qb[(q0 + l16) * 64 + ks * 32 + quad * 8];

    f32x4 O[4];
#pragma unroll
    for (int nt = 0; nt < 4; nt++) O[nt] = (f32x4){0.f, 0.f, 0.f, 0.f};
    float m_i[4] = {-1e30f, -1e30f, -1e30f, -1e30f};
    float l_i[4] = {0.f, 0.f, 0.f, 0.f};
    unsigned short* Pw = P[wave];

    for (int kt = 0; kt < 2048; kt += 64) {
        f32x4 S[4];
#pragma unroll
        for (int nt = 0; nt < 4; nt++) S[nt] = (f32x4){0.f, 0.f, 0.f, 0.f};
#pragma unroll
        for (int ks = 0; ks < 2; ks++)
#pragma unroll
            for (int nt = 0; nt < 4; nt++) {
                bf16x8 kf = *(const bf16x8*)&kb[(kt + nt * 16 + l16) * 64 + ks * 32 + quad * 8];
                S[nt] = __builtin_amdgcn_mfma_f32_16x16x32_bf16(qf[ks], kf, S[nt], 0, 0, 0);
            }
        // scale + additive mask + row max (rows live in 16-lane groups)
        float mx[4];
#pragma unroll
        for (int r = 0; r < 4; r++) {
#pragma unroll
            for (int nt = 0; nt < 4; nt++) {
                const float mv = mask[moff + r * 2048 + kt + nt * 16];
                S[nt][r] = S[nt][r] * 0.125f - 1e9f * mv;
            }
            float v = fmaxf(fmaxf(S[0][r], S[1][r]), fmaxf(S[2][r], S[3][r]));
            v = fmaxf(v, __shfl_xor(v, 1));
            v = fmaxf(v, __shfl_xor(v, 2));
            v = fmaxf(v, __shfl_xor(v, 4));
            v = fmaxf(v, __shfl_xor(v, 8));
            mx[r] = v;
        }
        float al[4];
#pragma unroll
        for (int r = 0; r < 4; r++) {
            const float mn = fmaxf(m_i[r], mx[r]);
            al[r] = __expf(m_i[r] - mn);
            m_i[r] = mn;
        }
#pragma unroll
        for (int nt = 0; nt < 4; nt++)
#pragma unroll
            for (int r = 0; r < 4; r++) S[nt][r] = __expf(S[nt][r] - m_i[r]);
#pragma unroll
        for (int r = 0; r < 4; r++) {
            float sv = S[0][r] + S[1][r] + S[2][r] + S[3][r];
            sv += __shfl_xor(sv, 1);
            sv += __shfl_xor(sv, 2);
            sv += __shfl_xor(sv, 4);
            sv += __shfl_xor(sv, 8);
            l_i[r] = l_i[r] * al[r] + sv;
        }
#pragma unroll
        for (int nt = 0; nt < 4; nt++)
#pragma unroll
            for (int r = 0; r < 4; r++) O[nt][r] *= al[r];
        // P (C-layout) -> LDS -> A-layout
#pragma unroll
        for (int nt = 0; nt < 4; nt++)
#pragma unroll
            for (int r = 0; r < 4; r++)
                Pw[(quad * 4 + r) * LDT + nt * 16 + l16] = f2bf(S[nt][r]);
#pragma unroll
        for (int ks = 0; ks < 2; ks++) {
            bf16x8 pf = *(const bf16x8*)&Pw[l16 * LDT + ks * 32 + quad * 8];
#pragma unroll
            for (int nt = 0; nt < 4; nt++) {
                bf16x8 vf = *(const bf16x8*)&vb[(nt * 16 + l16) * 2048 + kt + ks * 32 + quad * 8];
                O[nt] = __builtin_amdgcn_mfma_f32_16x16x32_bf16(pf, vf, O[nt], 0, 0, 0);
            }
        }
    }
    // epilogue: O /= l, write ctx bf16 [B,S,H*DV]
#pragma unroll
    for (int nt = 0; nt < 4; nt++)
#pragma unroll
        for (int r = 0; r < 4; r++) {
            const int row = q0 + quad * 4 + r;
            ctx[(size_t)(b * 2048 + row) * 1024 + h * 64 + nt * 16 + l16] = f2bf(O[nt][r] / l_i[r]);
        }
}

// ---------------------------------------------------------------------------
extern "C" void kernel_launch(void* const* d_in, const int* in_sizes, int n_in,
                              void* d_out, int out_size, void* d_ws, size_t ws_size,
                              hipStream_t stream)
{
    const float* Qin = (const float*)d_in[0];
    const float* Kin = (const float*)d_in[1];
    const float* Vin = (const float*)d_in[2];
    const float* Msk = (const float*)d_in[3];
    const float* Wq  = (const float*)d_in[4];
    const float* bq  = (const float*)d_in[5];
    const float* Wk  = (const float*)d_in[6];
    const float* bk  = (const float*)d_in[7];
    const float* Wv  = (const float*)d_in[8];
    const float* bv  = (const float*)d_in[9];
    const float* Wo  = (const float*)d_in[10];
    const float* bo  = (const float*)d_in[11];

    unsigned short* w = (unsigned short*)d_ws;
    unsigned short* wtq  = w;                       // 4 x 1M elems (bf16 weights^T)
    unsigned short* wtk  = w + (1u << 20);
    unsigned short* wtv  = w + 2u * (1u << 20);
    unsigned short* wto  = w + 3u * (1u << 20);
    unsigned short* qb   = w + 4u * (1u << 20);     // 4 x 8M elems
    unsigned short* kb   = qb + (1u << 23);
    unsigned short* vTb  = kb + (1u << 23);
    unsigned short* ctxb = vTb + (1u << 23);
    // total ws use: 8 MB + 64 MB = 72 MB

    prep_weights<<<dim3(32, 32, 4), 256, 0, stream>>>(Wq, Wk, Wv, Wo, wtq, wtk, wtv, wto);
    gemm128<0><<<dim3(64, 8), 256, 0, stream>>>(Qin, nullptr, wtq, bq, qb, nullptr);
    gemm128<1><<<dim3(64, 8), 256, 0, stream>>>(Kin, nullptr, wtk, bk, kb, nullptr);
    gemm128<2><<<dim3(64, 8), 256, 0, stream>>>(Vin, nullptr, wtv, bv, vTb, nullptr);
    attn_kernel<<<2048, 256, 0, stream>>>(qb, kb, vTb, Msk, ctxb);
    gemm128<3><<<dim3(64, 8), 256, 0, stream>>>(nullptr, ctxb, wto, bo, nullptr, (float*)d_out);
}